// Round 11
// baseline (284.804 us; speedup 1.0000x reference)
//
#include <hip/hip_runtime.h>
#include <stdint.h>

#define Bq   4
#define Nseq 2048
#define NH   16
#define HD   64
#define DIMD 1024

typedef float  f32x4   __attribute__((ext_vector_type(4)));
typedef float  f32x16  __attribute__((ext_vector_type(16)));
typedef __bf16 bf16x8  __attribute__((ext_vector_type(8)));
typedef short  s16x4   __attribute__((ext_vector_type(4)));

typedef __attribute__((address_space(1))) void as1_void;
typedef __attribute__((address_space(3))) void as3_void;

static __device__ __forceinline__ uint16_t f2bf(float f) {
    uint32_t u = __builtin_bit_cast(uint32_t, f);
    u += 0x7fffu + ((u >> 16) & 1u);          // RNE
    return (uint16_t)(u >> 16);
}

// truncation-pack two fp32 -> packed bf16x2 (p>=0, 1-ulp bias, cancels in p/l)
static __device__ __forceinline__ uint32_t pk2(float a, float b) {
    uint32_t ua = __builtin_bit_cast(uint32_t, a);
    uint32_t ub = __builtin_bit_cast(uint32_t, b);
    return (ua >> 16) | (ub & 0xffff0000u);
}

static __device__ __forceinline__ void asyncLoad16(const uint16_t* g, uint16_t* l) {
    __builtin_amdgcn_global_load_lds((as1_void*)g, (as3_void*)l, 16, 0, 0);
}

// ---------------------------------------------------------------------------
// cast fp32 -> bf16 : x (8388608) then Wq,Wk,Wv,Wo (4 x 1048576), dst contiguous
// Wq is pre-scaled by SCALE*log2(e) so attention can use exp2 on raw QK dots.
// ---------------------------------------------------------------------------
__global__ void cast_all(const float* __restrict__ x,
                         const float* __restrict__ wq, const float* __restrict__ wk,
                         const float* __restrict__ wv, const float* __restrict__ wo,
                         uint16_t* __restrict__ dst) {
    size_t i = ((size_t)blockIdx.x * blockDim.x + threadIdx.x) * 4;  // elem idx
    const float* src; size_t off; float scale = 1.0f;
    if (i < 8388608) { src = x; off = i; }
    else {
        size_t wI = i - 8388608;
        size_t wi = wI >> 20;
        off = wI & 1048575;
        src = (wi == 0) ? wq : (wi == 1) ? wk : (wi == 2) ? wv : wo;
        if (wi == 0) scale = 0.18033688011112042f;   // (1/sqrt(64)) * log2(e)
    }
    float4 v = *(const float4*)(src + off);
    ushort4 o;
    o.x = f2bf(v.x * scale); o.y = f2bf(v.y * scale);
    o.z = f2bf(v.z * scale); o.w = f2bf(v.w * scale);
    *(ushort4*)(dst + i) = o;
}

#define BARR()  __builtin_amdgcn_s_barrier()
#define SCB0()  __builtin_amdgcn_sched_barrier(0)
#define LGKM()  asm volatile("s_waitcnt lgkmcnt(0)" ::: "memory")
#define PRIO1() __builtin_amdgcn_s_setprio(1)
#define PRIO0() __builtin_amdgcn_s_setprio(0)

// ---------------------------------------------------------------------------
// QKV GEMM: 8-phase counted-vmcnt engine, BM=128 x BN=384 (R7, measured 65.2us,
// conflicts 0). Grid (64,8) = 512 blocks = 2 exact rounds at 1 block/CU.
// Units 8/K-tile (A 2, B 6), 2 staged per phase, vmcnt(4) at P4/P8 only;
// all fragment rows == ln mod 8 -> swizzle conflict-free.
// ---------------------------------------------------------------------------
__global__ __launch_bounds__(512, 2) void gemm_qkv384(
    const uint16_t* __restrict__ A, const uint16_t* __restrict__ W0,
    uint16_t* __restrict__ C0, uint16_t* __restrict__ vtb)
{
    __shared__ __align__(16) uint16_t Asm[2][2][4096];    // [buf][mh][64 rows x 64]
    __shared__ __align__(16) uint16_t Bsm[2][2][12288];   // [buf][nh][3 units x 64 x 64]

    const int t = threadIdx.x, lane = t & 63, w = t >> 6;
    const int wm = w >> 2, wn = w & 3;                    // 2 x 4 wave grid
    const int ln = lane & 15, l4 = lane >> 4;

    const int m0 = blockIdx.x * 128;
    const int n0 = blockIdx.y * 384;                      // global over Q|K|V rows

    const int srow = t >> 3;                              // 0..63
    const int sg   = (t & 7) ^ (srow & 7);
    const uint16_t* aBase = A + (size_t)(m0 + (srow >> 5)*64 + (srow & 31))*DIMD + sg*8;
    const uint16_t* bBase[3];
    #pragma unroll
    for (int j = 0; j < 3; ++j) {
        int f = j*64 + srow;
        int wnf = f / 48, off = f % 48;
        bBase[j] = W0 + (size_t)(n0 + wnf*96 + off)*DIMD + sg*8;
    }

#define SA(mh_, buf_, kk_) asyncLoad16(aBase + (size_t)(mh_)*32*DIMD + (kk_), \
        &Asm[buf_][mh_][t*8])
#define SB(nh_, j_, buf_, kk_) asyncLoad16(bBase[j_] + (size_t)(nh_)*48*DIMD + (kk_), \
        &Bsm[buf_][nh_][(j_)*4096 + t*8])

    SA(0,0,0); SA(1,0,0);
    SB(0,0,0,0); SB(0,1,0,0); SB(0,2,0,0);
    SB(1,0,0,0); SB(1,1,0,0); SB(1,2,0,0);
    SA(0,1,64);
    SB(0,0,1,64); SB(0,1,1,64); SB(0,2,1,64);
    asm volatile("s_waitcnt vmcnt(4)" ::: "memory");
    BARR();

    const int cs0 = ( l4      ^ (ln & 7)) * 8;
    const int cs1 = ((4 + l4) ^ (ln & 7)) * 8;
    const int awo = wm*2048 + ln*64;
    const int bwo = wn*3072 + ln*64;

    bf16x8 af[2][2], bf0[3][2], bf1[3][2];
    f32x4 acc[4][6] = {};

#define LDA(mh_, buf_)                                                         \
    _Pragma("unroll")                                                          \
    for (int mf = 0; mf < 2; ++mf) {                                           \
        af[mf][0] = *(const bf16x8*)(&Asm[buf_][mh_][awo + mf*1024 + cs0]);    \
        af[mf][1] = *(const bf16x8*)(&Asm[buf_][mh_][awo + mf*1024 + cs1]);    \
    }
#define LDB(nh_, buf_, BF)                                                     \
    _Pragma("unroll")                                                          \
    for (int nf = 0; nf < 3; ++nf) {                                           \
        BF[nf][0] = *(const bf16x8*)(&Bsm[buf_][nh_][bwo + nf*1024 + cs0]);    \
        BF[nf][1] = *(const bf16x8*)(&Bsm[buf_][nh_][bwo + nf*1024 + cs1]);    \
    }
#define MFMA12(mh_, nh_, BF)                                                   \
    _Pragma("unroll")                                                          \
    for (int mf = 0; mf < 2; ++mf)                                             \
        _Pragma("unroll")                                                      \
        for (int nf = 0; nf < 3; ++nf) {                                       \
            acc[(mh_)*2+mf][(nh_)*3+nf] = __builtin_amdgcn_mfma_f32_16x16x32_bf16( \
                af[mf][0], BF[nf][0], acc[(mh_)*2+mf][(nh_)*3+nf], 0,0,0);     \
            acc[(mh_)*2+mf][(nh_)*3+nf] = __builtin_amdgcn_mfma_f32_16x16x32_bf16( \
                af[mf][1], BF[nf][1], acc[(mh_)*2+mf][(nh_)*3+nf], 0,0,0);     \
        }

    #pragma unroll 1
    for (int i = 0; i < 8; ++i) {
        const int kk1 = i*128 + 64, kk2 = i*128 + 128, kk3 = i*128 + 192;
        const bool pf = (i < 7);

        LDA(0,0); LDB(0,0,bf0);
        SA(1,1,kk1); SB(1,0,1,kk1);
        BARR(); LGKM(); SCB0();
        PRIO1(); MFMA12(0,0,bf0); PRIO0();
        SCB0(); BARR();

        LDB(1,0,bf1);
        SB(1,1,1,kk1); SB(1,2,1,kk1);
        BARR(); LGKM(); SCB0();
        PRIO1(); MFMA12(0,1,bf1); PRIO0();
        SCB0(); BARR();

        LDA(1,0);
        if (pf) { SA(0,0,kk2); SB(0,0,0,kk2); }
        BARR(); LGKM(); SCB0();
        PRIO1(); MFMA12(1,0,bf0); PRIO0();
        SCB0(); BARR();

        if (pf) { SB(0,1,0,kk2); SB(0,2,0,kk2); }
        BARR(); SCB0();
        PRIO1(); MFMA12(1,1,bf1); PRIO0();
        SCB0();
        if (pf) { asm volatile("s_waitcnt vmcnt(4)" ::: "memory"); }
        else    { asm volatile("s_waitcnt vmcnt(0)" ::: "memory"); }
        BARR();

        LDA(0,1); LDB(0,1,bf0);
        if (pf) { SA(1,0,kk2); SB(1,0,0,kk2); }
        BARR(); LGKM(); SCB0();
        PRIO1(); MFMA12(0,0,bf0); PRIO0();
        SCB0(); BARR();

        LDB(1,1,bf1);
        if (pf) { SB(1,1,0,kk2); SB(1,2,0,kk2); }
        BARR(); LGKM(); SCB0();
        PRIO1(); MFMA12(0,1,bf1); PRIO0();
        SCB0(); BARR();

        LDA(1,1);
        if (pf) { SA(0,1,kk3); SB(0,0,1,kk3); }
        BARR(); LGKM(); SCB0();
        PRIO1(); MFMA12(1,0,bf0); PRIO0();
        SCB0(); BARR();

        if (pf) { SB(0,1,1,kk3); SB(0,2,1,kk3); }
        BARR(); SCB0();
        PRIO1(); MFMA12(1,1,bf1); PRIO0();
        SCB0();
        if (pf) { asm volatile("s_waitcnt vmcnt(4)" ::: "memory"); BARR(); }
    }

#undef SA
#undef SB
#undef LDA
#undef LDB
#undef MFMA12

    // ---- epilogue: C/D 16x16 layout col = ln, row = l4*4 + r ----
    #pragma unroll
    for (int mh = 0; mh < 2; ++mh)
      #pragma unroll
      for (int mf = 0; mf < 2; ++mf)
        #pragma unroll
        for (int nh = 0; nh < 2; ++nh)
          #pragma unroll
          for (int nf = 0; nf < 3; ++nf) {
              const f32x4 a4 = acc[mh*2+mf][nh*3+nf];
              int rowg = m0 + wm*64 + mh*32 + mf*16 + l4*4;   // token (+r)
              int colg = n0 + wn*96 + nh*48 + nf*16 + ln;     // global out dim
              if (colg < 2048) {                               // Q or K, row-major
                  uint16_t* C = C0 + (size_t)(colg >> 10) * 8388608;
                  int col = colg & 1023;
                  #pragma unroll
                  for (int r = 0; r < 4; ++r)
                      C[(size_t)(rowg + r)*1024 + col] = f2bf(a4[r]);
              } else {                                         // V, transposed
                  int dg = colg - 2048;
                  int bb = rowg >> 11, nn = rowg & 2047;
                  ushort4 o4;
                  o4.x = f2bf(a4[0]); o4.y = f2bf(a4[1]);
                  o4.z = f2bf(a4[2]); o4.w = f2bf(a4[3]);
                  *(ushort4*)(vtb + ((size_t)(bb*1024 + dg))*Nseq + nn) = o4;
              }
          }
}

// ---------------------------------------------------------------------------
// Output projection: 8-phase engine, BM=256 x BN=128 -> grid (32,8) = 256
// blocks = exactly one round at 1 block/CU (96 KiB LDS). R9-measured good.
// ---------------------------------------------------------------------------
__global__ __launch_bounds__(512, 2) void gemm_out256(
    const uint16_t* __restrict__ A, const uint16_t* __restrict__ W0,
    float* __restrict__ C)
{
    __shared__ __align__(16) uint16_t Asm[2][2][8192];    // [buf][mh][2 units x 64 x 64]
    __shared__ __align__(16) uint16_t Bsm[2][2][4096];    // [buf][nh][64 rows x 64]

    const int t = threadIdx.x, lane = t & 63, w = t >> 6;
    const int wm = w >> 2, wn = w & 3;                    // 2 x 4 wave grid
    const int ln = lane & 15, l4 = lane >> 4;

    const int m0 = blockIdx.x * 256;
    const int n0 = blockIdx.y * 128;

    const int srow = t >> 3;                              // 0..63
    const int sg   = (t & 7) ^ (srow & 7);
    const uint16_t* aBase = A + (size_t)(m0 + srow)*DIMD + sg*8;
    const uint16_t* bBase = W0 + (size_t)(n0 + (srow >> 4)*32 + (srow & 15))*DIMD + sg*8;

#define SA(mh_, j_, buf_, kk_) asyncLoad16(aBase + (size_t)((j_)*128 + (mh_)*64)*DIMD + (kk_), \
        &Asm[buf_][mh_][(j_)*4096 + t*8])
#define SB(nh_, buf_, kk_) asyncLoad16(bBase + (size_t)(nh_)*16*DIMD + (kk_), \
        &Bsm[buf_][nh_][t*8])

    // prologue: tile0 = B(0), A-mh0(0), A-mh1(0); then B(1), A-mh0(1)
    SB(0,0,0); SB(1,0,0);
    SA(0,0,0,0); SA(0,1,0,0);
    SA(1,0,0,0); SA(1,1,0,0);
    SB(0,1,64); SB(1,1,64);
    SA(0,0,1,64); SA(0,1,1,64);
    asm volatile("s_waitcnt vmcnt(4)" ::: "memory");
    BARR();

    const int cs0 = ( l4      ^ (ln & 7)) * 8;
    const int cs1 = ((4 + l4) ^ (ln & 7)) * 8;
    const int awo = wm*4096 + ln*64;                      // + mf*1024 + cs
    const int bwo = wn*1024 + ln*64;                      // + cs

    bf16x8 af[4][2], bfA[2], bfB[2];
    f32x4 acc[8][2] = {};

#define LDA(mh_, buf_)                                                         \
    _Pragma("unroll")                                                          \
    for (int mf = 0; mf < 4; ++mf) {                                           \
        af[mf][0] = *(const bf16x8*)(&Asm[buf_][mh_][awo + mf*1024 + cs0]);    \
        af[mf][1] = *(const bf16x8*)(&Asm[buf_][mh_][awo + mf*1024 + cs1]);    \
    }
#define LDB(nh_, buf_, BF)                                                     \
    BF[0] = *(const bf16x8*)(&Bsm[buf_][nh_][bwo + cs0]);                      \
    BF[1] = *(const bf16x8*)(&Bsm[buf_][nh_][bwo + cs1]);
#define MFMA8(mh_, nh_, BF)                                                    \
    _Pragma("unroll")                                                          \
    for (int mf = 0; mf < 4; ++mf) {                                           \
        acc[(mh_)*4+mf][nh_] = __builtin_amdgcn_mfma_f32_16x16x32_bf16(        \
            af[mf][0], BF[0], acc[(mh_)*4+mf][nh_], 0,0,0);                    \
        acc[(mh_)*4+mf][nh_] = __builtin_amdgcn_mfma_f32_16x16x32_bf16(        \
            af[mf][1], BF[1], acc[(mh_)*4+mf][nh_], 0,0,0);                    \
    }

    #pragma unroll 1
    for (int i = 0; i < 8; ++i) {                         // tiles 2i (b0), 2i+1 (b1)
        const int kk1 = i*128 + 64, kk2 = i*128 + 128, kk3 = i*128 + 192;
        const bool pf2 = (i < 7);                         // tile 2i+2 exists
        const bool pf3 = (i < 7);                         // tile 2i+3 exists

        // -------- P1: b0 (mh0,nh0); stage A-mh1(2i+1)->b1 --------
        LDA(0,0); LDB(0,0,bfA);
        SA(1,0,1,kk1); SA(1,1,1,kk1);
        BARR(); LGKM(); SCB0();
        PRIO1(); MFMA8(0,0,bfA); PRIO0();
        SCB0(); BARR();

        // -------- P2: b0 (mh0,nh1) --------
        LDB(1,0,bfB);
        BARR(); LGKM(); SCB0();
        PRIO1(); MFMA8(0,1,bfB); PRIO0();
        SCB0(); BARR();

        // -------- P3: b0 (mh1,nh0); stage B(2i+2), A-mh0(2i+2)->b0 --------
        LDA(1,0);
        if (pf2) { SB(0,0,kk2); SB(1,0,kk2); SA(0,0,0,kk2); SA(0,1,0,kk2); }
        BARR(); LGKM(); SCB0();
        PRIO1(); MFMA8(1,0,bfA); PRIO0();
        SCB0(); BARR();

        // -------- P4: b0 (mh1,nh1); vmcnt forces tile 2i+1 --------
        BARR(); SCB0();
        PRIO1(); MFMA8(1,1,bfB); PRIO0();
        SCB0();
        if (pf2) { asm volatile("s_waitcnt vmcnt(4)" ::: "memory"); }
        else     { asm volatile("s_waitcnt vmcnt(0)" ::: "memory"); }
        BARR();

        // -------- P5: b1 (mh0,nh0); stage A-mh1(2i+2)->b0 --------
        LDA(0,1); LDB(0,1,bfA);
        if (pf2) { SA(1,0,0,kk2); SA(1,1,0,kk2); }
        BARR(); LGKM(); SCB0();
        PRIO1(); MFMA8(0,0,bfA); PRIO0();
        SCB0(); BARR();

        // -------- P6: b1 (mh0,nh1) --------
        LDB(1,1,bfB);
        BARR(); LGKM(); SCB0();
        PRIO1(); MFMA8(0,1,bfB); PRIO0();
        SCB0(); BARR();

        // -------- P7: b1 (mh1,nh0); stage B(2i+3), A-mh0(2i+3)->b1 --------
        LDA(1,1);
        if (pf3) { SB(0,1,kk3); SB(1,1,kk3); SA(0,0,1,kk3); SA(0,1,1,kk3); }
        BARR(); LGKM(); SCB0();
        PRIO1(); MFMA8(1,0,bfA); PRIO0();
        SCB0(); BARR();

        // -------- P8: b1 (mh1,nh1); vmcnt forces tile 2i+2 --------
        BARR(); SCB0();
        PRIO1(); MFMA8(1,1,bfB); PRIO0();
        SCB0();
        if (pf3) { asm volatile("s_waitcnt vmcnt(4)" ::: "memory"); BARR(); }
    }

#undef SA
#undef SB
#undef LDA
#undef LDB
#undef MFMA8

    // ---- epilogue: C/D 16x16 layout col = ln, row = l4*4 + r; fp32 out ----
    #pragma unroll
    for (int mh = 0; mh < 2; ++mh)
      #pragma unroll
      for (int mf = 0; mf < 4; ++mf)
        #pragma unroll
        for (int nh = 0; nh < 2; ++nh) {
            const f32x4 a4 = acc[mh*4+mf][nh];
            int rowg = m0 + wm*128 + mh*64 + mf*16 + l4*4;
            int colg = n0 + wn*32 + nh*16 + ln;
            #pragma unroll
            for (int r = 0; r < 4; ++r)
                C[(size_t)(rowg + r)*1024 + colg] = a4[r];
        }
}

// ---------------------------------------------------------------------------
// Flash attention, causal, no-max online softmax, S^T formulation.
// R11 change: QBLK 128 -> 256 (8 waves, 512 thr). Per-wave inner code and the
// R10 T15 pipeline are UNCHANGED; the same 64x64 K/V LDS tiles now feed 2x the
// compute, so stage+vmcnt(0)+barrier events per FLOP halve (sum k-tiles per bh
// 272 -> 144) and K/V L2 traffic halves. Occupancy 12 -> 16-24 waves/CU.
// Grid (64 bh, 8 q-slots) = 512 blocks ~2/CU; per-CU pairing (y, y+4) with
// qi = {7-y | y-4} gives exactly 36 k-tiles per CU (4(a+1)+4(b+1), a+b=7).
// Q (256x64 = 32 KB) staged through Kb-flat (24 KB) + Vb[0] (8 KB) scratch;
// region select by wave-uniform w<=5 (max Kb-region row = 191 at w=5,qt=1,c=15).
// Peel wait vmcnt(2): STAGE_KV now issues 1 K + 1 V load per thread.
// ---------------------------------------------------------------------------
__global__ __launch_bounds__(512, 4) void attn(
    const uint16_t* __restrict__ Q, const uint16_t* __restrict__ K,
    const uint16_t* __restrict__ Vt, uint16_t* __restrict__ O)
{
    __shared__ __align__(16) uint16_t Kb[3][64*64];   // 24 KB (Q scratch rows 0-191)
    __shared__ __align__(16) uint16_t Vb[3][64*64];   // 24 KB (Vb[0] = Q scratch rows 192-255)

    const int t = threadIdx.x, lane = t & 63, w = t >> 6;   // w in 0..7
    const int quad = lane >> 4, c = lane & 15;
    const int y = blockIdx.y;                                // 0..7
    const int qi = (y < 4) ? (7 - y) : (y - 4);              // pair sums = 7
    const int q0 = qi * 256;
    const int bh = blockIdx.x, b = bh >> 4, h = bh & 15;
    const size_t tokBase = (size_t)b * Nseq;
    const int hcol = h * HD;
    uint16_t* KbF = (uint16_t*)Kb;                           // flat 12288 elems
    uint16_t* VbF = (uint16_t*)Vb;

    #define STAGE_KV(k0_, buf_)                                             \
        {                                                                    \
            int row = t >> 3, gg = (t & 7) ^ (row & 7);                      \
            asyncLoad16(K + (tokBase + (k0_) + row)*DIMD + hcol + gg*8,      \
                        Kb[buf_] + (size_t)t*8);                             \
            asyncLoad16(Vt + ((size_t)bh*HD + row)*Nseq + (k0_) + gg*8,      \
                        Vb[buf_] + (size_t)t*8);                             \
        }

    // ---- stage Q (256x64) through scratch, grab fragments, then free it ----
    #pragma unroll
    for (int i = 0; i < 4; ++i) {
        int row = t >> 3, gg = (t & 7) ^ (row & 7);
        const uint16_t* src = Q + (tokBase + q0 + i*64 + row)*DIMD + hcol + gg*8;
        int off = i*4096 + t*8;
        if (i < 3) asyncLoad16(src, KbF + off);
        else       asyncLoad16(src, VbF + (off - 12288));
    }
    __syncthreads();                                  // Q landed
    bf16x8 qf[2][2];
    #pragma unroll
    for (int qt = 0; qt < 2; ++qt)
        #pragma unroll
        for (int ks = 0; ks < 2; ++ks) {
            int row = w*32 + qt*16 + c;               // 0..255; w<=5 => row<=191
            int pos = (ks*4 + quad) ^ (row & 7);
            const uint16_t* p = (w <= 5) ? (KbF + (size_t)(row*8 + pos)*8)
                                         : (VbF + (size_t)((row - 192)*8 + pos)*8);
            qf[qt][ks] = *(const bf16x8*)p;
        }
    __syncthreads();                                  // all reads done, scratch free

    const int wrow0 = q0 + w*32;
    const int end   = 4*qi + 4;                       // multiple of 4, >= 4
    const int lastw = (wrow0 + 31) >> 6;              // last tile this wave computes
    STAGE_KV(0, 0);                                   // tiles 0 and 1 in flight
    STAGE_KV(64, 1);

    f32x4  o[2][4] = {};
    float  l_lane[2] = {0.f, 0.f};
    s16x4  pbA[2][4], pbB[2][4];

    // QK^T + causal mask + exp2 + pack for tile j_ into PB (reads Ks_)
    #define QKSM(j_, PB, KSP)                                                  \
    {                                                                          \
        const uint16_t* Ks_ = (KSP);                                           \
        const int k0_ = (j_) * 64;                                             \
        f32x4 sv[2][4] = {};                                                   \
        __builtin_amdgcn_s_setprio(1);                                         \
        _Pragma("unroll")                                                      \
        for (int nt = 0; nt < 4; ++nt)                                         \
            _Pragma("unroll")                                                  \
            for (int ks = 0; ks < 2; ++ks) {                                   \
                int row = nt*16 + c;                                           \
                int pos = (ks*4 + quad) ^ (row & 7);                           \
                bf16x8 kf = *(const bf16x8*)(Ks_ + (size_t)(row*8 + pos)*8);   \
                sv[0][nt] = __builtin_amdgcn_mfma_f32_16x16x32_bf16(kf, qf[0][ks], sv[0][nt], 0,0,0); \
                sv[1][nt] = __builtin_amdgcn_mfma_f32_16x16x32_bf16(kf, qf[1][ks], sv[1][nt], 0,0,0); \
            }                                                                  \
        __builtin_amdgcn_s_setprio(0);                                         \
        if (k0_ + 63 > wrow0) {                                                \
            _Pragma("unroll")                                                  \
            for (int qt = 0; qt < 2; ++qt)                                     \
                _Pragma("unroll")                                              \
                for (int nt = 0; nt < 4; ++nt)                                 \
                    _Pragma("unroll")                                          \
                    for (int r = 0; r < 4; ++r) {                              \
                        int kvg = k0_ + nt*16 + quad*4 + r;                    \
                        int qg  = wrow0 + qt*16 + c;                           \
                        if (kvg > qg) sv[qt][nt][r] = -340.0f;                 \
                    }                                                          \
        }                                                                      \
        _Pragma("unroll")                                                      \
        for (int qt = 0; qt < 2; ++qt)                                         \
            _Pragma("unroll")                                                  \
            for (int nt = 0; nt < 4; ++nt) {                                   \
                float p0 = __builtin_amdgcn_exp2f(sv[qt][nt][0]);              \
                float p1 = __builtin_amdgcn_exp2f(sv[qt][nt][1]);              \
                float p2 = __builtin_amdgcn_exp2f(sv[qt][nt][2]);              \
                float p3 = __builtin_amdgcn_exp2f(sv[qt][nt][3]);              \
                l_lane[qt] += (p0 + p1) + (p2 + p3);                           \
                union { uint32_t u[2]; s16x4 v; } pu;                          \
                pu.u[0] = pk2(p0, p1);                                         \
                pu.u[1] = pk2(p2, p3);                                         \
                PB[qt][nt] = pu.v;                                             \
            }                                                                  \
    }

    // O^T += V^T.P^T using PB (reads Vs_)
    #define PVOP(PB, VSP)                                                      \
    {                                                                          \
        const uint16_t* Vs_ = (VSP);                                           \
        __builtin_amdgcn_s_setprio(1);                                         \
        _Pragma("unroll")                                                      \
        for (int s4 = 0; s4 < 4; ++s4)                                         \
            _Pragma("unroll")                                                  \
            for (int dt = 0; dt < 4; ++dt) {                                   \
                int row = dt*16 + c;                                           \
                int chunk = s4*2 + (quad >> 1);                                \
                int pos = chunk ^ (row & 7);                                   \
                s16x4 vf = *(const s16x4*)(Vs_ + (size_t)(row*8 + pos)*8 + (quad & 1)*4); \
                o[0][dt] = __builtin_amdgcn_mfma_f32_16x16x16bf16_1k(vf, PB[0][s4], o[0][dt], 0,0,0); \
                o[1][dt] = __builtin_amdgcn_mfma_f32_16x16x16bf16_1k(vf, PB[1][s4], o[1][dt], 0,0,0); \
            }                                                                  \
        __builtin_amdgcn_s_setprio(0);                                         \
    }

    // ---- peel: QK+softmax for tile 0 (tile 0 = oldest 2 of 4 in flight) ----
    asm volatile("s_waitcnt vmcnt(2)\n\ts_barrier" ::: "memory");
    QKSM(0, pbA, Kb[0]);

    int b0 = 0, b1 = 1, b2 = 2;
    for (int kt = 0; kt < end; kt += 2) {
        // ---- even iter: QK(kt+1)->pbB ; PV(kt)<-pbA ----
        asm volatile("s_waitcnt vmcnt(0)\n\ts_barrier" ::: "memory");
        if (kt + 2 < end) { STAGE_KV((kt+2)*64, b2); }
        if (kt + 1 <= lastw) { QKSM(kt+1, pbB, Kb[b1]); }
        if (kt     <= lastw) { PVOP(pbA, Vb[b0]); }
        { int tmp = b0; b0 = b1; b1 = b2; b2 = tmp; }

        // ---- odd iter: QK(kt+2)->pbA ; PV(kt+1)<-pbB ----
        asm volatile("s_waitcnt vmcnt(0)\n\ts_barrier" ::: "memory");
        if (kt + 3 < end) { STAGE_KV((kt+3)*64, b2); }
        if (kt + 2 <= lastw) { QKSM(kt+2, pbA, Kb[b1]); }
        if (kt + 1 <= lastw) { PVOP(pbB, Vb[b0]); }
        { int tmp = b0; b0 = b1; b1 = b2; b2 = tmp; }
    }

    // ---- epilogue: reduce l over quads, scale, store O^T packed ----
    #pragma unroll
    for (int qt = 0; qt < 2; ++qt) {
        float l = l_lane[qt];
        l += __shfl_xor(l, 16);
        l += __shfl_xor(l, 32);
        float inv = 1.0f / l;
        int tok = (int)(q0 + w*32 + qt*16 + c);
        #pragma unroll
        for (int dt = 0; dt < 4; ++dt) {
            ushort4 o4;
            o4.x = f2bf(o[qt][dt][0] * inv);
            o4.y = f2bf(o[qt][dt][1] * inv);
            o4.z = f2bf(o[qt][dt][2] * inv);
            o4.w = f2bf(o[qt][dt][3] * inv);
            *(ushort4*)(O + (tokBase + tok)*DIMD + hcol + dt*16 + quad*4) = o4;
        }
    }
    #undef STAGE_KV
    #undef QKSM
    #undef PVOP
}

// ---------------------------------------------------------------------------
extern "C" void kernel_launch(void* const* d_in, const int* in_sizes, int n_in,
                              void* d_out, int out_size, void* d_ws, size_t ws_size,
                              hipStream_t stream) {
    const float* x  = (const float*)d_in[0];
    // d_in[1] = causal tril mask, deterministic -> handled analytically
    const float* Wq = (const float*)d_in[2];
    const float* Wk = (const float*)d_in[3];
    const float* Wv = (const float*)d_in[4];
    const float* Wo = (const float*)d_in[5];

    uint16_t* ws  = (uint16_t*)d_ws;
    uint16_t* xb  = ws;                      // x bf16 (later reused as attn out)
    uint16_t* wqb = ws + 8388608;            // Wq,Wk,Wv,Wo bf16 contiguous
    uint16_t* wob = wqb + 3*1048576;
    uint16_t* qb  = ws + 12582912;           // Q
    uint16_t* kb  = qb + 8388608;            // K
    uint16_t* vtb = kb + 8388608;            // V transposed per (b,h)
    uint16_t* ab  = xb;                      // attention output reuses xb

    cast_all<<<12288, 256, 0, stream>>>(x, Wq, Wk, Wv, Wo, ws);

    // QKV: 128x384 8-phase counted-vmcnt kernel; 512 blocks = 2 exact rounds.
    gemm_qkv384<<<dim3(64, 8), 512, 0, stream>>>(xb, wqb, qb, vtb);

    // attn: QBLK=256, 8 waves; 512 blocks ~2/CU, per-CU k-tile sums balanced.
    attn<<<dim3(64, 8), 512, 0, stream>>>(qb, kb, vtb, ab);

    // Out-projection: 256x128 8-phase kernel; 256 blocks = 1 exact round.
    gemm_out256<<<dim3(32, 8), 512, 0, stream>>>(ab, wob, (float*)d_out);
}

// Round 12
// 238.038 us; speedup vs baseline: 1.1965x; 1.1965x over previous
//
#include <hip/hip_runtime.h>
#include <stdint.h>

#define Bq   4
#define Nseq 2048
#define NH   16
#define HD   64
#define DIMD 1024

typedef float  f32x4   __attribute__((ext_vector_type(4)));
typedef float  f32x16  __attribute__((ext_vector_type(16)));
typedef __bf16 bf16x8  __attribute__((ext_vector_type(8)));
typedef short  s16x4   __attribute__((ext_vector_type(4)));

typedef __attribute__((address_space(1))) void as1_void;
typedef __attribute__((address_space(3))) void as3_void;

static __device__ __forceinline__ uint16_t f2bf(float f) {
    uint32_t u = __builtin_bit_cast(uint32_t, f);
    u += 0x7fffu + ((u >> 16) & 1u);          // RNE
    return (uint16_t)(u >> 16);
}

// truncation-pack two fp32 -> packed bf16x2 (p>=0, 1-ulp bias, cancels in p/l)
static __device__ __forceinline__ uint32_t pk2(float a, float b) {
    uint32_t ua = __builtin_bit_cast(uint32_t, a);
    uint32_t ub = __builtin_bit_cast(uint32_t, b);
    return (ua >> 16) | (ub & 0xffff0000u);
}

static __device__ __forceinline__ void asyncLoad16(const uint16_t* g, uint16_t* l) {
    __builtin_amdgcn_global_load_lds((as1_void*)g, (as3_void*)l, 16, 0, 0);
}

// ---------------------------------------------------------------------------
// cast fp32 -> bf16 : x (8388608) then Wq,Wk,Wv,Wo (4 x 1048576), dst contiguous
// Wq is pre-scaled by SCALE*log2(e) so attention can use exp2 on raw QK dots.
// ---------------------------------------------------------------------------
__global__ void cast_all(const float* __restrict__ x,
                         const float* __restrict__ wq, const float* __restrict__ wk,
                         const float* __restrict__ wv, const float* __restrict__ wo,
                         uint16_t* __restrict__ dst) {
    size_t i = ((size_t)blockIdx.x * blockDim.x + threadIdx.x) * 4;  // elem idx
    const float* src; size_t off; float scale = 1.0f;
    if (i < 8388608) { src = x; off = i; }
    else {
        size_t wI = i - 8388608;
        size_t wi = wI >> 20;
        off = wI & 1048575;
        src = (wi == 0) ? wq : (wi == 1) ? wk : (wi == 2) ? wv : wo;
        if (wi == 0) scale = 0.18033688011112042f;   // (1/sqrt(64)) * log2(e)
    }
    float4 v = *(const float4*)(src + off);
    ushort4 o;
    o.x = f2bf(v.x * scale); o.y = f2bf(v.y * scale);
    o.z = f2bf(v.z * scale); o.w = f2bf(v.w * scale);
    *(ushort4*)(dst + i) = o;
}

#define BARR()  __builtin_amdgcn_s_barrier()
#define SCB0()  __builtin_amdgcn_sched_barrier(0)
#define LGKM()  asm volatile("s_waitcnt lgkmcnt(0)" ::: "memory")
#define PRIO1() __builtin_amdgcn_s_setprio(1)
#define PRIO0() __builtin_amdgcn_s_setprio(0)

// ---------------------------------------------------------------------------
// QKV GEMM: 8-phase counted-vmcnt engine, BM=128 x BN=384 (R7, measured 65.2us,
// conflicts 0). Grid (64,8) = 512 blocks = 2 exact rounds at 1 block/CU.
// Units 8/K-tile (A 2, B 6), 2 staged per phase, vmcnt(4) at P4/P8 only;
// all fragment rows == ln mod 8 -> swizzle conflict-free.
// ---------------------------------------------------------------------------
__global__ __launch_bounds__(512, 2) void gemm_qkv384(
    const uint16_t* __restrict__ A, const uint16_t* __restrict__ W0,
    uint16_t* __restrict__ C0, uint16_t* __restrict__ vtb)
{
    __shared__ __align__(16) uint16_t Asm[2][2][4096];    // [buf][mh][64 rows x 64]
    __shared__ __align__(16) uint16_t Bsm[2][2][12288];   // [buf][nh][3 units x 64 x 64]

    const int t = threadIdx.x, lane = t & 63, w = t >> 6;
    const int wm = w >> 2, wn = w & 3;                    // 2 x 4 wave grid
    const int ln = lane & 15, l4 = lane >> 4;

    const int m0 = blockIdx.x * 128;
    const int n0 = blockIdx.y * 384;                      // global over Q|K|V rows

    const int srow = t >> 3;                              // 0..63
    const int sg   = (t & 7) ^ (srow & 7);
    const uint16_t* aBase = A + (size_t)(m0 + (srow >> 5)*64 + (srow & 31))*DIMD + sg*8;
    const uint16_t* bBase[3];
    #pragma unroll
    for (int j = 0; j < 3; ++j) {
        int f = j*64 + srow;
        int wnf = f / 48, off = f % 48;
        bBase[j] = W0 + (size_t)(n0 + wnf*96 + off)*DIMD + sg*8;
    }

#define SA(mh_, buf_, kk_) asyncLoad16(aBase + (size_t)(mh_)*32*DIMD + (kk_), \
        &Asm[buf_][mh_][t*8])
#define SB(nh_, j_, buf_, kk_) asyncLoad16(bBase[j_] + (size_t)(nh_)*48*DIMD + (kk_), \
        &Bsm[buf_][nh_][(j_)*4096 + t*8])

    SA(0,0,0); SA(1,0,0);
    SB(0,0,0,0); SB(0,1,0,0); SB(0,2,0,0);
    SB(1,0,0,0); SB(1,1,0,0); SB(1,2,0,0);
    SA(0,1,64);
    SB(0,0,1,64); SB(0,1,1,64); SB(0,2,1,64);
    asm volatile("s_waitcnt vmcnt(4)" ::: "memory");
    BARR();

    const int cs0 = ( l4      ^ (ln & 7)) * 8;
    const int cs1 = ((4 + l4) ^ (ln & 7)) * 8;
    const int awo = wm*2048 + ln*64;
    const int bwo = wn*3072 + ln*64;

    bf16x8 af[2][2], bf0[3][2], bf1[3][2];
    f32x4 acc[4][6] = {};

#define LDA(mh_, buf_)                                                         \
    _Pragma("unroll")                                                          \
    for (int mf = 0; mf < 2; ++mf) {                                           \
        af[mf][0] = *(const bf16x8*)(&Asm[buf_][mh_][awo + mf*1024 + cs0]);    \
        af[mf][1] = *(const bf16x8*)(&Asm[buf_][mh_][awo + mf*1024 + cs1]);    \
    }
#define LDB(nh_, buf_, BF)                                                     \
    _Pragma("unroll")                                                          \
    for (int nf = 0; nf < 3; ++nf) {                                           \
        BF[nf][0] = *(const bf16x8*)(&Bsm[buf_][nh_][bwo + nf*1024 + cs0]);    \
        BF[nf][1] = *(const bf16x8*)(&Bsm[buf_][nh_][bwo + nf*1024 + cs1]);    \
    }
#define MFMA12(mh_, nh_, BF)                                                   \
    _Pragma("unroll")                                                          \
    for (int mf = 0; mf < 2; ++mf)                                             \
        _Pragma("unroll")                                                      \
        for (int nf = 0; nf < 3; ++nf) {                                       \
            acc[(mh_)*2+mf][(nh_)*3+nf] = __builtin_amdgcn_mfma_f32_16x16x32_bf16( \
                af[mf][0], BF[nf][0], acc[(mh_)*2+mf][(nh_)*3+nf], 0,0,0);     \
            acc[(mh_)*2+mf][(nh_)*3+nf] = __builtin_amdgcn_mfma_f32_16x16x32_bf16( \
                af[mf][1], BF[nf][1], acc[(mh_)*2+mf][(nh_)*3+nf], 0,0,0);     \
        }

    #pragma unroll 1
    for (int i = 0; i < 8; ++i) {
        const int kk1 = i*128 + 64, kk2 = i*128 + 128, kk3 = i*128 + 192;
        const bool pf = (i < 7);

        LDA(0,0); LDB(0,0,bf0);
        SA(1,1,kk1); SB(1,0,1,kk1);
        BARR(); LGKM(); SCB0();
        PRIO1(); MFMA12(0,0,bf0); PRIO0();
        SCB0(); BARR();

        LDB(1,0,bf1);
        SB(1,1,1,kk1); SB(1,2,1,kk1);
        BARR(); LGKM(); SCB0();
        PRIO1(); MFMA12(0,1,bf1); PRIO0();
        SCB0(); BARR();

        LDA(1,0);
        if (pf) { SA(0,0,kk2); SB(0,0,0,kk2); }
        BARR(); LGKM(); SCB0();
        PRIO1(); MFMA12(1,0,bf0); PRIO0();
        SCB0(); BARR();

        if (pf) { SB(0,1,0,kk2); SB(0,2,0,kk2); }
        BARR(); SCB0();
        PRIO1(); MFMA12(1,1,bf1); PRIO0();
        SCB0();
        if (pf) { asm volatile("s_waitcnt vmcnt(4)" ::: "memory"); }
        else    { asm volatile("s_waitcnt vmcnt(0)" ::: "memory"); }
        BARR();

        LDA(0,1); LDB(0,1,bf0);
        if (pf) { SA(1,0,kk2); SB(1,0,0,kk2); }
        BARR(); LGKM(); SCB0();
        PRIO1(); MFMA12(0,0,bf0); PRIO0();
        SCB0(); BARR();

        LDB(1,1,bf1);
        if (pf) { SB(1,1,0,kk2); SB(1,2,0,kk2); }
        BARR(); LGKM(); SCB0();
        PRIO1(); MFMA12(0,1,bf1); PRIO0();
        SCB0(); BARR();

        LDA(1,1);
        if (pf) { SA(0,1,kk3); SB(0,0,1,kk3); }
        BARR(); LGKM(); SCB0();
        PRIO1(); MFMA12(1,0,bf0); PRIO0();
        SCB0(); BARR();

        if (pf) { SB(0,1,1,kk3); SB(0,2,1,kk3); }
        BARR(); SCB0();
        PRIO1(); MFMA12(1,1,bf1); PRIO0();
        SCB0();
        if (pf) { asm volatile("s_waitcnt vmcnt(4)" ::: "memory"); BARR(); }
    }

#undef SA
#undef SB
#undef LDA
#undef LDB
#undef MFMA12

    // ---- epilogue: C/D 16x16 layout col = ln, row = l4*4 + r ----
    #pragma unroll
    for (int mh = 0; mh < 2; ++mh)
      #pragma unroll
      for (int mf = 0; mf < 2; ++mf)
        #pragma unroll
        for (int nh = 0; nh < 2; ++nh)
          #pragma unroll
          for (int nf = 0; nf < 3; ++nf) {
              const f32x4 a4 = acc[mh*2+mf][nh*3+nf];
              int rowg = m0 + wm*64 + mh*32 + mf*16 + l4*4;   // token (+r)
              int colg = n0 + wn*96 + nh*48 + nf*16 + ln;     // global out dim
              if (colg < 2048) {                               // Q or K, row-major
                  uint16_t* C = C0 + (size_t)(colg >> 10) * 8388608;
                  int col = colg & 1023;
                  #pragma unroll
                  for (int r = 0; r < 4; ++r)
                      C[(size_t)(rowg + r)*1024 + col] = f2bf(a4[r]);
              } else {                                         // V, transposed
                  int dg = colg - 2048;
                  int bb = rowg >> 11, nn = rowg & 2047;
                  ushort4 o4;
                  o4.x = f2bf(a4[0]); o4.y = f2bf(a4[1]);
                  o4.z = f2bf(a4[2]); o4.w = f2bf(a4[3]);
                  *(ushort4*)(vtb + ((size_t)(bb*1024 + dg))*Nseq + nn) = o4;
              }
          }
}

// ---------------------------------------------------------------------------
// Output projection: 8-phase engine, BM=256 x BN=128 -> grid (32,8) = 256
// blocks = exactly one round at 1 block/CU (96 KiB LDS). R9-measured good.
// ---------------------------------------------------------------------------
__global__ __launch_bounds__(512, 2) void gemm_out256(
    const uint16_t* __restrict__ A, const uint16_t* __restrict__ W0,
    float* __restrict__ C)
{
    __shared__ __align__(16) uint16_t Asm[2][2][8192];    // [buf][mh][2 units x 64 x 64]
    __shared__ __align__(16) uint16_t Bsm[2][2][4096];    // [buf][nh][64 rows x 64]

    const int t = threadIdx.x, lane = t & 63, w = t >> 6;
    const int wm = w >> 2, wn = w & 3;                    // 2 x 4 wave grid
    const int ln = lane & 15, l4 = lane >> 4;

    const int m0 = blockIdx.x * 256;
    const int n0 = blockIdx.y * 128;

    const int srow = t >> 3;                              // 0..63
    const int sg   = (t & 7) ^ (srow & 7);
    const uint16_t* aBase = A + (size_t)(m0 + srow)*DIMD + sg*8;
    const uint16_t* bBase = W0 + (size_t)(n0 + (srow >> 4)*32 + (srow & 15))*DIMD + sg*8;

#define SA(mh_, j_, buf_, kk_) asyncLoad16(aBase + (size_t)((j_)*128 + (mh_)*64)*DIMD + (kk_), \
        &Asm[buf_][mh_][(j_)*4096 + t*8])
#define SB(nh_, buf_, kk_) asyncLoad16(bBase + (size_t)(nh_)*16*DIMD + (kk_), \
        &Bsm[buf_][nh_][t*8])

    // prologue: tile0 = B(0), A-mh0(0), A-mh1(0); then B(1), A-mh0(1)
    SB(0,0,0); SB(1,0,0);
    SA(0,0,0,0); SA(0,1,0,0);
    SA(1,0,0,0); SA(1,1,0,0);
    SB(0,1,64); SB(1,1,64);
    SA(0,0,1,64); SA(0,1,1,64);
    asm volatile("s_waitcnt vmcnt(4)" ::: "memory");
    BARR();

    const int cs0 = ( l4      ^ (ln & 7)) * 8;
    const int cs1 = ((4 + l4) ^ (ln & 7)) * 8;
    const int awo = wm*4096 + ln*64;                      // + mf*1024 + cs
    const int bwo = wn*1024 + ln*64;                      // + cs

    bf16x8 af[4][2], bfA[2], bfB[2];
    f32x4 acc[8][2] = {};

#define LDA(mh_, buf_)                                                         \
    _Pragma("unroll")                                                          \
    for (int mf = 0; mf < 4; ++mf) {                                           \
        af[mf][0] = *(const bf16x8*)(&Asm[buf_][mh_][awo + mf*1024 + cs0]);    \
        af[mf][1] = *(const bf16x8*)(&Asm[buf_][mh_][awo + mf*1024 + cs1]);    \
    }
#define LDB(nh_, buf_, BF)                                                     \
    BF[0] = *(const bf16x8*)(&Bsm[buf_][nh_][bwo + cs0]);                      \
    BF[1] = *(const bf16x8*)(&Bsm[buf_][nh_][bwo + cs1]);
#define MFMA8(mh_, nh_, BF)                                                    \
    _Pragma("unroll")                                                          \
    for (int mf = 0; mf < 4; ++mf) {                                           \
        acc[(mh_)*4+mf][nh_] = __builtin_amdgcn_mfma_f32_16x16x32_bf16(        \
            af[mf][0], BF[0], acc[(mh_)*4+mf][nh_], 0,0,0);                    \
        acc[(mh_)*4+mf][nh_] = __builtin_amdgcn_mfma_f32_16x16x32_bf16(        \
            af[mf][1], BF[1], acc[(mh_)*4+mf][nh_], 0,0,0);                    \
    }

    #pragma unroll 1
    for (int i = 0; i < 8; ++i) {                         // tiles 2i (b0), 2i+1 (b1)
        const int kk1 = i*128 + 64, kk2 = i*128 + 128, kk3 = i*128 + 192;
        const bool pf2 = (i < 7);                         // tile 2i+2 exists
        const bool pf3 = (i < 7);                         // tile 2i+3 exists

        // -------- P1: b0 (mh0,nh0); stage A-mh1(2i+1)->b1 --------
        LDA(0,0); LDB(0,0,bfA);
        SA(1,0,1,kk1); SA(1,1,1,kk1);
        BARR(); LGKM(); SCB0();
        PRIO1(); MFMA8(0,0,bfA); PRIO0();
        SCB0(); BARR();

        // -------- P2: b0 (mh0,nh1) --------
        LDB(1,0,bfB);
        BARR(); LGKM(); SCB0();
        PRIO1(); MFMA8(0,1,bfB); PRIO0();
        SCB0(); BARR();

        // -------- P3: b0 (mh1,nh0); stage B(2i+2), A-mh0(2i+2)->b0 --------
        LDA(1,0);
        if (pf2) { SB(0,0,kk2); SB(1,0,kk2); SA(0,0,0,kk2); SA(0,1,0,kk2); }
        BARR(); LGKM(); SCB0();
        PRIO1(); MFMA8(1,0,bfA); PRIO0();
        SCB0(); BARR();

        // -------- P4: b0 (mh1,nh1); vmcnt forces tile 2i+1 --------
        BARR(); SCB0();
        PRIO1(); MFMA8(1,1,bfB); PRIO0();
        SCB0();
        if (pf2) { asm volatile("s_waitcnt vmcnt(4)" ::: "memory"); }
        else     { asm volatile("s_waitcnt vmcnt(0)" ::: "memory"); }
        BARR();

        // -------- P5: b1 (mh0,nh0); stage A-mh1(2i+2)->b0 --------
        LDA(0,1); LDB(0,1,bfA);
        if (pf2) { SA(1,0,0,kk2); SA(1,1,0,kk2); }
        BARR(); LGKM(); SCB0();
        PRIO1(); MFMA8(0,0,bfA); PRIO0();
        SCB0(); BARR();

        // -------- P6: b1 (mh0,nh1) --------
        LDB(1,1,bfB);
        BARR(); LGKM(); SCB0();
        PRIO1(); MFMA8(0,1,bfB); PRIO0();
        SCB0(); BARR();

        // -------- P7: b1 (mh1,nh0); stage B(2i+3), A-mh0(2i+3)->b1 --------
        LDA(1,1);
        if (pf3) { SB(0,1,kk3); SB(1,1,kk3); SA(0,0,1,kk3); SA(0,1,1,kk3); }
        BARR(); LGKM(); SCB0();
        PRIO1(); MFMA8(1,0,bfA); PRIO0();
        SCB0(); BARR();

        // -------- P8: b1 (mh1,nh1); vmcnt forces tile 2i+2 --------
        BARR(); SCB0();
        PRIO1(); MFMA8(1,1,bfB); PRIO0();
        SCB0();
        if (pf3) { asm volatile("s_waitcnt vmcnt(4)" ::: "memory"); BARR(); }
    }

#undef SA
#undef SB
#undef LDA
#undef LDB
#undef MFMA8

    // ---- epilogue: C/D 16x16 layout col = ln, row = l4*4 + r; fp32 out ----
    #pragma unroll
    for (int mh = 0; mh < 2; ++mh)
      #pragma unroll
      for (int mf = 0; mf < 4; ++mf)
        #pragma unroll
        for (int nh = 0; nh < 2; ++nh) {
            const f32x4 a4 = acc[mh*4+mf][nh];
            int rowg = m0 + wm*128 + mh*64 + mf*16 + l4*4;
            int colg = n0 + wn*32 + nh*16 + ln;
            #pragma unroll
            for (int r = 0; r < 4; ++r)
                C[(size_t)(rowg + r)*1024 + colg] = a4[r];
        }
}

// ---------------------------------------------------------------------------
// Flash attention, causal, no-max online softmax, S^T formulation.
// R10 configuration (measured best: wall 241.3): QBLK=128, 4 waves, triple-
// buffered K/V, T15 att[2] double-pipeline (QK/SM of t+1 overlaps PV of t),
// PV on mfma_16x16x16bf16_1k. R11's QBLK=256 regressed 60% (occupancy 4->2
// blocks/CU killed cross-block latency hiding) -- reverted.
// ---------------------------------------------------------------------------
__global__ __launch_bounds__(256, 3) void attn(
    const uint16_t* __restrict__ Q, const uint16_t* __restrict__ K,
    const uint16_t* __restrict__ Vt, uint16_t* __restrict__ O)
{
    __shared__ __align__(16) uint16_t Kb[3][64*64];   // 24 KB (first 16 KB = Q scratch)
    __shared__ __align__(16) uint16_t Vb[3][64*64];   // 24 KB (V^T tiles, rows=d)

    const int t = threadIdx.x, lane = t & 63, w = t >> 6;
    const int quad = lane >> 4, c = lane & 15;
    const int y = blockIdx.y;
    const int qi = (y < 4) ? (15 - y) : (y < 8) ? (y + 4) : (y < 12) ? (y - 4) : (15 - y);
    const int q0 = qi * 128;
    const int bh = blockIdx.x, b = bh >> 4, h = bh & 15;
    const size_t tokBase = (size_t)b * Nseq;
    const int hcol = h * HD;
    uint16_t* Qs = (uint16_t*)Kb;                    // 16 KB scratch (Kb[0..1])

    #define STAGE_KV(k0_, buf_)                                             \
        _Pragma("unroll")                                                    \
        for (int i = 0; i < 2; ++i) {                                        \
            int s = t + 256*i;                                               \
            int row = s >> 3, gg = (s & 7) ^ (row & 7);                      \
            asyncLoad16(K + (tokBase + (k0_) + row)*DIMD + hcol + gg*8,      \
                        Kb[buf_] + (size_t)(w*64 + 256*i)*8);                \
            asyncLoad16(Vt + ((size_t)bh*HD + row)*Nseq + (k0_) + gg*8,      \
                        Vb[buf_] + (size_t)(w*64 + 256*i)*8);                \
        }

    // ---- stage Q (128x64) through scratch, grab fragments, then free it ----
    #pragma unroll
    for (int i = 0; i < 4; ++i) {
        int s = t + 256*i;
        int row = s >> 3, gg = (s & 7) ^ (row & 7);
        asyncLoad16(Q + (tokBase + q0 + row)*DIMD + hcol + gg*8,
                    Qs + (size_t)(w*64 + 256*i)*8);
    }
    __syncthreads();                                  // Q landed
    bf16x8 qf[2][2];
    #pragma unroll
    for (int qt = 0; qt < 2; ++qt)
        #pragma unroll
        for (int ks = 0; ks < 2; ++ks) {
            int row = w*32 + qt*16 + c;
            int pos = (ks*4 + quad) ^ (row & 7);
            qf[qt][ks] = *(const bf16x8*)(Qs + (size_t)(row*8 + pos)*8);
        }
    __syncthreads();                                  // all reads done, scratch free

    const int wrow0 = q0 + w*32;
    const int end   = 2*qi + 2;                       // even, >= 2
    const int lastw = (wrow0 + 31) >> 6;              // last tile this wave computes
    STAGE_KV(0, 0);                                   // tiles 0 and 1 in flight
    STAGE_KV(64, 1);

    f32x4  o[2][4] = {};
    float  l_lane[2] = {0.f, 0.f};
    s16x4  pbA[2][4], pbB[2][4];

    // QK^T + causal mask + exp2 + pack for tile j_ into PB (reads Ks_)
    #define QKSM(j_, PB, KSP)                                                  \
    {                                                                          \
        const uint16_t* Ks_ = (KSP);                                           \
        const int k0_ = (j_) * 64;                                             \
        f32x4 sv[2][4] = {};                                                   \
        __builtin_amdgcn_s_setprio(1);                                         \
        _Pragma("unroll")                                                      \
        for (int nt = 0; nt < 4; ++nt)                                         \
            _Pragma("unroll")                                                  \
            for (int ks = 0; ks < 2; ++ks) {                                   \
                int row = nt*16 + c;                                           \
                int pos = (ks*4 + quad) ^ (row & 7);                           \
                bf16x8 kf = *(const bf16x8*)(Ks_ + (size_t)(row*8 + pos)*8);   \
                sv[0][nt] = __builtin_amdgcn_mfma_f32_16x16x32_bf16(kf, qf[0][ks], sv[0][nt], 0,0,0); \
                sv[1][nt] = __builtin_amdgcn_mfma_f32_16x16x32_bf16(kf, qf[1][ks], sv[1][nt], 0,0,0); \
            }                                                                  \
        __builtin_amdgcn_s_setprio(0);                                         \
        if (k0_ + 63 > wrow0) {                                                \
            _Pragma("unroll")                                                  \
            for (int qt = 0; qt < 2; ++qt)                                     \
                _Pragma("unroll")                                              \
                for (int nt = 0; nt < 4; ++nt)                                 \
                    _Pragma("unroll")                                          \
                    for (int r = 0; r < 4; ++r) {                              \
                        int kvg = k0_ + nt*16 + quad*4 + r;                    \
                        int qg  = wrow0 + qt*16 + c;                           \
                        if (kvg > qg) sv[qt][nt][r] = -340.0f;                 \
                    }                                                          \
        }                                                                      \
        _Pragma("unroll")                                                      \
        for (int qt = 0; qt < 2; ++qt)                                         \
            _Pragma("unroll")                                                  \
            for (int nt = 0; nt < 4; ++nt) {                                   \
                float p0 = __builtin_amdgcn_exp2f(sv[qt][nt][0]);              \
                float p1 = __builtin_amdgcn_exp2f(sv[qt][nt][1]);              \
                float p2 = __builtin_amdgcn_exp2f(sv[qt][nt][2]);              \
                float p3 = __builtin_amdgcn_exp2f(sv[qt][nt][3]);              \
                l_lane[qt] += (p0 + p1) + (p2 + p3);                           \
                union { uint32_t u[2]; s16x4 v; } pu;                          \
                pu.u[0] = pk2(p0, p1);                                         \
                pu.u[1] = pk2(p2, p3);                                         \
                PB[qt][nt] = pu.v;                                             \
            }                                                                  \
    }

    // O^T += V^T.P^T for tile kt_ using PB (reads Vs_)
    #define PVOP(PB, VSP)                                                      \
    {                                                                          \
        const uint16_t* Vs_ = (VSP);                                           \
        __builtin_amdgcn_s_setprio(1);                                         \
        _Pragma("unroll")                                                      \
        for (int s4 = 0; s4 < 4; ++s4)                                         \
            _Pragma("unroll")                                                  \
            for (int dt = 0; dt < 4; ++dt) {                                   \
                int row = dt*16 + c;                                           \
                int chunk = s4*2 + (quad >> 1);                                \
                int pos = chunk ^ (row & 7);                                   \
                s16x4 vf = *(const s16x4*)(Vs_ + (size_t)(row*8 + pos)*8 + (quad & 1)*4); \
                o[0][dt] = __builtin_amdgcn_mfma_f32_16x16x16bf16_1k(vf, PB[0][s4], o[0][dt], 0,0,0); \
                o[1][dt] = __builtin_amdgcn_mfma_f32_16x16x16bf16_1k(vf, PB[1][s4], o[1][dt], 0,0,0); \
            }                                                                  \
        __builtin_amdgcn_s_setprio(0);                                         \
    }

    // ---- peel: QK+softmax for tile 0 (tile 0 forced by own vmcnt + barrier) ----
    asm volatile("s_waitcnt vmcnt(4)\n\ts_barrier" ::: "memory");
    QKSM(0, pbA, Kb[0]);

    int b0 = 0, b1 = 1, b2 = 2;
    for (int kt = 0; kt < end; kt += 2) {
        // ---- even iter: QK(kt+1)->pbB ; PV(kt)<-pbA ----
        asm volatile("s_waitcnt vmcnt(0)\n\ts_barrier" ::: "memory");
        if (kt + 2 < end) { STAGE_KV((kt+2)*64, b2); }
        if (kt + 1 <= lastw) { QKSM(kt+1, pbB, Kb[b1]); }
        if (kt     <= lastw) { PVOP(pbA, Vb[b0]); }
        { int tmp = b0; b0 = b1; b1 = b2; b2 = tmp; }

        // ---- odd iter: QK(kt+2)->pbA ; PV(kt+1)<-pbB ----
        asm volatile("s_waitcnt vmcnt(0)\n\ts_barrier" ::: "memory");
        if (kt + 3 < end) { STAGE_KV((kt+3)*64, b2); }
        if (kt + 2 <= lastw) { QKSM(kt+2, pbA, Kb[b1]); }
        if (kt + 1 <= lastw) { PVOP(pbB, Vb[b0]); }
        { int tmp = b0; b0 = b1; b1 = b2; b2 = tmp; }
    }

    // ---- epilogue: reduce l over quads, scale, store O^T packed ----
    #pragma unroll
    for (int qt = 0; qt < 2; ++qt) {
        float l = l_lane[qt];
        l += __shfl_xor(l, 16);
        l += __shfl_xor(l, 32);
        float inv = 1.0f / l;
        int tok = (int)(q0 + w*32 + qt*16 + c);
        #pragma unroll
        for (int dt = 0; dt < 4; ++dt) {
            ushort4 o4;
            o4.x = f2bf(o[qt][dt][0] * inv);
            o4.y = f2bf(o[qt][dt][1] * inv);
            o4.z = f2bf(o[qt][dt][2] * inv);
            o4.w = f2bf(o[qt][dt][3] * inv);
            *(ushort4*)(O + (tokBase + tok)*DIMD + hcol + dt*16 + quad*4) = o4;
        }
    }
    #undef STAGE_KV
    #undef QKSM
    #undef PVOP
}

// ---------------------------------------------------------------------------
extern "C" void kernel_launch(void* const* d_in, const int* in_sizes, int n_in,
                              void* d_out, int out_size, void* d_ws, size_t ws_size,
                              hipStream_t stream) {
    const float* x  = (const float*)d_in[0];
    // d_in[1] = causal tril mask, deterministic -> handled analytically
    const float* Wq = (const float*)d_in[2];
    const float* Wk = (const float*)d_in[3];
    const float* Wv = (const float*)d_in[4];
    const float* Wo = (const float*)d_in[5];

    uint16_t* ws  = (uint16_t*)d_ws;
    uint16_t* xb  = ws;                      // x bf16 (later reused as attn out)
    uint16_t* wqb = ws + 8388608;            // Wq,Wk,Wv,Wo bf16 contiguous
    uint16_t* wob = wqb + 3*1048576;
    uint16_t* qb  = ws + 12582912;           // Q
    uint16_t* kb  = qb + 8388608;            // K
    uint16_t* vtb = kb + 8388608;            // V transposed per (b,h)
    uint16_t* ab  = xb;                      // attention output reuses xb

    cast_all<<<12288, 256, 0, stream>>>(x, Wq, Wk, Wv, Wo, ws);

    // QKV: 128x384 8-phase counted-vmcnt kernel; 512 blocks = 2 exact rounds.
    gemm_qkv384<<<dim3(64, 8), 512, 0, stream>>>(xb, wqb, qb, vtb);

    // attn: QBLK=128, 4 waves, T15 pipeline (R10 best-measured config).
    attn<<<dim3(64, 16), 256, 0, stream>>>(qb, kb, vtb, ab);

    // Out-projection: 256x128 8-phase kernel; 256 blocks = 1 exact round.
    gemm_out256<<<dim3(32, 8), 512, 0, stream>>>(ab, wob, (float*)d_out);
}